// Round 10
// baseline (307.837 us; speedup 1.0000x reference)
//
#include <hip/hip_runtime.h>

#define TOKENS 65536
#define DIM 64
#define NCODE 1024
// fp16-screen margin (unscaled). Screen error bound: ~192 f32 roundings x
// ulp(3e5 scaled)/2^21 ~ 2.9e-6 worst-case; 1e-5 gives 3.4x headroom.
#define MARGIN 1e-5f
#define MARGINS (MARGIN * 2097152.0f)   // scaled-domain threshold (x 2^21)

#define OUT_IDX_OFF ((size_t)TOKENS * DIM)          // 4194304
#define OUT_LOSS_OFF (OUT_IDX_OFF + TOKENS)         // 4259840

// ws layout (bytes):
#define WS_LOSS   0        // double
#define WS_FLAGC  8        // uint (unused r10, still zeroed)
#define WS_DONEA  12       // uint (global finisher counter)
#define WS_DGRP   16       // uint[512] (unused r10; still zeroed) -> 2064
#define WS_BNORM  2064     // f32[1024] -> 6160 (unscaled, exact path)
#define WS_BNS    6160     // f32[1024] -> 10256 (x2^21, screen)
#define WS_CHI    10256    // ushort[65536] -> 141328 (fp16 hi of -8192*c)
#define WS_CLO    141328   // ushort[65536] -> 272400 (fp16 lo)

typedef __attribute__((ext_vector_type(8))) short short8;
typedef __attribute__((ext_vector_type(8))) _Float16 half8;
typedef __attribute__((ext_vector_type(4))) float f32x4;

static __device__ __forceinline__ half8 as_h8(short8 v) {
    return __builtin_bit_cast(half8, v);
}

// ---------------------------------------------------------------------------
// numpy-bitwise f32 sum-of-squares — VERIFIED absmax=0 (round 2). Do not touch.
// ---------------------------------------------------------------------------
__device__ __forceinline__ float np_sumsq64(const float* __restrict__ x) {
#pragma clang fp contract(off)
    float r[8];
#pragma unroll
    for (int j = 0; j < 8; ++j) r[j] = x[j] * x[j];
#pragma unroll
    for (int i = 8; i < 64; i += 8) {
#pragma unroll
        for (int j = 0; j < 8; ++j) {
            float sq = x[i + j] * x[i + j];
            r[j] = r[j] + sq;
        }
    }
    return ((r[0] + r[1]) + (r[2] + r[3])) + ((r[4] + r[5]) + (r[6] + r[7]));
}

// ---------------------------------------------------------------------------
// Prep v2 (UNCHANGED, verified): codebook -> fp16 hi/lo A-frags of (-2*4096*C)
// + bnorm (unscaled, exact path) + bns (= bnorm * 2^21, screen).
// ---------------------------------------------------------------------------
__global__ __launch_bounds__(256) void vq_prep(
    const float* __restrict__ cb, unsigned short* __restrict__ chi,
    unsigned short* __restrict__ clo, float* __restrict__ bnorm,
    float* __restrict__ bns,
    unsigned int* __restrict__ ctrl /* 516 u32 at ws+0 */) {
    int tid = blockIdx.x * 256 + threadIdx.x;   // 0..65535
    if (tid < 516) ctrl[tid] = 0u;
    int j = tid & 7;
    int L = (tid >> 3) & 63;
    int cs = tid >> 9;          // 0..127
    int s = cs & 1, c = cs >> 1;
    int code = c * 16 + (L & 15);
    int d = s * 32 + (L >> 4) * 8 + j;
    float v = -8192.0f * cb[(size_t)code * DIM + d];   // -2c * 4096 (exact)
    _Float16 h = (_Float16)v;                          // RN f32->f16
    float hf = (float)h;
    float lo;
    {
#pragma clang fp contract(off)
        lo = v - hf;                                   // exact in f32
    }
    _Float16 l = (_Float16)lo;
    chi[tid] = __builtin_bit_cast(unsigned short, h);
    clo[tid] = __builtin_bit_cast(unsigned short, l);

    if (tid < NCODE) {
        float bn = np_sumsq64(cb + (size_t)tid * DIM);
        bnorm[tid] = bn;
        bns[tid] = bn * 2097152.0f;                    // x 2^21 (exact)
    }
}

__device__ __forceinline__ void top2_merge(float& a1, float& a2, int& ai,
                                           float b1, float b2, int bi) {
    float n1 = fminf(a1, b1);
    float n2 = fminf(fmaxf(a1, b1), fminf(a2, b2));
    ai = (b1 < a1) ? bi : ai;   // ties keep a (exact ties get flagged anyway)
    a1 = n1; a2 = n2;
}

__device__ __forceinline__ unsigned long long shfl_down_u64(unsigned long long v, int off) {
    unsigned int lo = (unsigned int)v, hi = (unsigned int)(v >> 32);
    lo = __shfl_down(lo, off);
    hi = __shfl_down(hi, off);
    return ((unsigned long long)hi << 32) | lo;
}

// ---------------------------------------------------------------------------
// Fused screen + inline exact, v13 (r10). Screen = r3/v9 VERBATIM (best
// verified 51.5us; r4/r5/r7 structural variants all regressed). Change:
// flagged tokens (~110 of 65536, ~0.1/block) are resolved INSIDE this
// kernel — flags stay in LDS, and the block runs the r9-verified
// block-per-token exact routine (v6 arithmetic copied verbatim: same FMA
// chain -> same bits; block u64-min = same argmin/tie rule) for each of
// its flagged slots. Removes the 3rd kernel launch, the 8192-block sweep,
// and all flag_count/flag_list/packed_min global traffic. Last block to
// finish (done_all) writes the final loss (verified pattern). Loss =
// same multiset of f64 atomics, different order (verified harmless).
// ---------------------------------------------------------------------------
__global__ __launch_bounds__(256, 4) void vq_fast(
    const float* __restrict__ z, const float* __restrict__ cb,
    const unsigned short* __restrict__ cfrag_hi,
    const unsigned short* __restrict__ cfrag_lo,
    const float* __restrict__ bnorm_s, const float* __restrict__ bnorm,
    float* __restrict__ out, double* __restrict__ loss_sum,
    unsigned int* __restrict__ done_all) {
    __shared__ short8 sh_hi[2][512];   // [buf][(cc*2+step)*64 + lane], 8KB each
    __shared__ short8 sh_lo[2][512];
    __shared__ float bn_lds[NCODE];
    __shared__ int s_best[64];
    __shared__ int s_flag[64];
    __shared__ int s_flist[64];
    __shared__ unsigned int s_fcnt;
    __shared__ float zsh[68];
    __shared__ float s_zs;
    __shared__ unsigned long long s_pk[4];
    __shared__ unsigned long long s_min;

    const int tid = threadIdx.x;
    const int lane = tid & 63;
    const int w = tid >> 6;
    const int t0 = blockIdx.x * 64;
    const int tw = t0 + w * 16;              // this wave's 16 tokens
    const int col = lane & 15;
    const int quad = lane >> 4;

    if (tid == 0) s_fcnt = 0u;

    // stage scaled bnorm into LDS (4 KB)
    ((float4*)bn_lds)[tid] = ((const float4*)bnorm_s)[tid];

    // token B-fragments (fp16 hi/lo of z*512), 2 K-steps, in registers
    half8 zhi[2], zlo[2];
#pragma unroll
    for (int s = 0; s < 2; ++s) {
        const float* zp = z + (size_t)(tw + col) * DIM + s * 32 + quad * 8;
        float4 f0 = ((const float4*)zp)[0];
        float4 f1 = ((const float4*)zp)[1];
        float f[8] = {f0.x, f0.y, f0.z, f0.w, f1.x, f1.y, f1.z, f1.w};
        half8 hh8, ll8;
#pragma unroll
        for (int j = 0; j < 8; ++j) {
            float sv = f[j] * 512.0f;        // exact pow2 scale
            _Float16 hh = (_Float16)sv;      // RN
            float hf = (float)hh;
            float lo;
            {
#pragma clang fp contract(off)
                lo = sv - hf;                // exact in f32
            }
            hh8[j] = hh;
            ll8[j] = (_Float16)lo;
        }
        zhi[s] = hh8; zlo[s] = ll8;
    }

    const short8* CH = (const short8*)cfrag_hi;   // 4096 short8 (64 chunks)
    const short8* CL = (const short8*)cfrag_lo;

    // stage group 0 (4 chunks = 512 short8 per array; 2 per thread per array)
    {
        short8 a0 = CH[tid], a1 = CH[tid + 256];
        short8 b0 = CL[tid], b1 = CL[tid + 256];
        sh_hi[0][tid] = a0; sh_hi[0][tid + 256] = a1;
        sh_lo[0][tid] = b0; sh_lo[0][tid + 256] = b1;
    }
    __syncthreads();

    float m1 = 3.0e38f, m2 = 3.0e38f;
    int bi = 0;
    const int koff = quad * 4;

    for (int g = 0; g < 16; ++g) {
        const int buf = g & 1;
        short8 a0, a1, b0, b1;
        if (g < 15) {               // issue next group's loads first
            const int base = (g + 1) * 512 + tid;
            a0 = CH[base]; a1 = CH[base + 256];
            b0 = CL[base]; b1 = CL[base + 256];
        }
#pragma unroll
        for (int cc = 0; cc < 4; ++cc) {
            const int c = g * 4 + cc;
            short8 ch0 = sh_hi[buf][(cc * 2 + 0) * 64 + lane];
            short8 ch1 = sh_hi[buf][(cc * 2 + 1) * 64 + lane];
            short8 cl0 = sh_lo[buf][(cc * 2 + 0) * 64 + lane];
            short8 cl1 = sh_lo[buf][(cc * 2 + 1) * 64 + lane];
            const int cbase = c * 16 + koff;
            const f32x4 bn = *(const f32x4*)&bn_lds[cbase];
            f32x4 acc = bn;
            acc = __builtin_amdgcn_mfma_f32_16x16x32_f16(as_h8(ch0), zhi[0], acc, 0, 0, 0);
            acc = __builtin_amdgcn_mfma_f32_16x16x32_f16(as_h8(cl0), zhi[0], acc, 0, 0, 0);
            acc = __builtin_amdgcn_mfma_f32_16x16x32_f16(as_h8(ch0), zlo[0], acc, 0, 0, 0);
            acc = __builtin_amdgcn_mfma_f32_16x16x32_f16(as_h8(ch1), zhi[1], acc, 0, 0, 0);
            acc = __builtin_amdgcn_mfma_f32_16x16x32_f16(as_h8(cl1), zhi[1], acc, 0, 0, 0);
            acc = __builtin_amdgcn_mfma_f32_16x16x32_f16(as_h8(ch1), zlo[1], acc, 0, 0, 0);
#pragma unroll
            for (int i = 0; i < 4; ++i) {
                float u = acc[i];
                float om1 = m1;
                bool lt = u < om1;
                float fm = fminf(m2, u);
                m2 = lt ? om1 : fm;
                m1 = lt ? u : om1;
                bi = lt ? (cbase + i) : bi;
            }
        }
        if (g < 15) {
            sh_hi[buf ^ 1][tid] = a0; sh_hi[buf ^ 1][tid + 256] = a1;
            sh_lo[buf ^ 1][tid] = b0; sh_lo[buf ^ 1][tid + 256] = b1;
            __syncthreads();
        }
    }

    // in-wave quad merge (lanes l, l^16, l^32, l^48 share a token column)
    {
        float a1 = m1, a2 = m2;
        int ai = bi;
        {
            float o1 = __shfl_xor(a1, 16); float o2 = __shfl_xor(a2, 16);
            int oi = __shfl_xor(ai, 16);
            top2_merge(a1, a2, ai, o1, o2, oi);
        }
        {
            float o1 = __shfl_xor(a1, 32); float o2 = __shfl_xor(a2, 32);
            int oi = __shfl_xor(ai, 32);
            top2_merge(a1, a2, ai, o1, o2, oi);
        }
        if (quad == 0) {
            const int slot = w * 16 + col;
            int fl = (a2 - a1) < MARGINS;
            if (fl) {
                unsigned int p = atomicAdd(&s_fcnt, 1u);   // LDS, block-scope
                s_flist[p] = slot;
            }
            s_best[slot] = ai;
            s_flag[slot] = fl;
        }
    }
    __syncthreads();

    // epilogue: 2 threads per token, 32 floats each (r6-verified partial
    // structure); flagged deferred to inline exact below.
    const int et = tid >> 1, h = tid & 1;
    float loss_t = 0.0f;
    if (et < 64 && !s_flag[et]) {
        const int B = s_best[et];
        const float4* cq  = (const float4*)(cb + (size_t)B * DIM + h * 32);
        const float4* zq4 = (const float4*)(z + (size_t)(t0 + et) * DIM + h * 32);
        float4* o4 = (float4*)(out + (size_t)(t0 + et) * DIM + h * 32);
#pragma unroll
        for (int jj = 0; jj < 8; ++jj) {
#pragma clang fp contract(off)
            float4 cc = cq[jj];
            float4 zz = zq4[jj];
            float d0 = cc.x - zz.x, d1 = cc.y - zz.y;
            float d2 = cc.z - zz.z, d3 = cc.w - zz.w;
            float4 o;
            o.x = zz.x + d0; o.y = zz.y + d1;
            o.z = zz.z + d2; o.w = zz.w + d3;
            o4[jj] = o;
            loss_t = __fmaf_rn(d0, d0, loss_t);
            loss_t = __fmaf_rn(d1, d1, loss_t);
            loss_t = __fmaf_rn(d2, d2, loss_t);
            loss_t = __fmaf_rn(d3, d3, loss_t);
        }
        if (h == 0) out[OUT_IDX_OFF + t0 + et] = (float)B;
    }
#pragma unroll
    for (int off = 32; off > 0; off >>= 1)
        loss_t += __shfl_down(loss_t, off);
    if (lane == 0 && w < 2) atomicAdd(loss_sum, (double)loss_t);

    // ---- inline exact pass for this block's flagged tokens (usually 0/1).
    // Arithmetic copied VERBATIM from r9-verified v6 (same bits).
    const unsigned int nf = s_fcnt;
    for (unsigned int fi = 0; fi < nf; ++fi) {
        __syncthreads();                       // zsh reuse across iterations
        const int t = t0 + s_flist[fi];
        if (tid < 4) {
            const float4* zp4 = (const float4*)(z + (size_t)t * DIM + tid * 16);
            float4* dst = (float4*)(zsh + tid * 16);
#pragma unroll
            for (int e = 0; e < 4; ++e) dst[e] = zp4[e];
        }
        __syncthreads();
        if (tid == 0) s_zs = np_sumsq64(zsh);
        __syncthreads();

        const float szs = s_zs;
        const float* zp = zsh;
        unsigned long long pk = ~0ull;

        for (int e = 0; e < 4; ++e) {
            const int k = e * 256 + tid;          // code index
            float row[DIM];
            {
                const float4* c4 = (const float4*)(cb + (size_t)k * DIM);
#pragma unroll
                for (int j = 0; j < 16; ++j) {
                    float4 v = c4[j];
                    row[4 * j + 0] = v.x; row[4 * j + 1] = v.y;
                    row[4 * j + 2] = v.z; row[4 * j + 3] = v.w;
                }
            }
            const float bnk = bnorm[k];

            float l16[16];
#pragma unroll
            for (int g2 = 0; g2 < 4; ++g2) {
                float4 v0 = ((const float4*)(zp + 4 * g2))[0];
                float4 v1 = ((const float4*)(zp + 16 + 4 * g2))[0];
                float4 v2 = ((const float4*)(zp + 32 + 4 * g2))[0];
                float4 v3 = ((const float4*)(zp + 48 + 4 * g2))[0];
                float a0[4] = {v0.x, v0.y, v0.z, v0.w};
                float a1[4] = {v1.x, v1.y, v1.z, v1.w};
                float a2[4] = {v2.x, v2.y, v2.z, v2.w};
                float a3[4] = {v3.x, v3.y, v3.z, v3.w};
#pragma unroll
                for (int ee = 0; ee < 4; ++ee) {
#pragma clang fp contract(off)
                    int jj = 4 * g2 + ee;
                    float acc = a3[ee] * row[48 + jj];
                    acc = __fmaf_rn(a2[ee], row[32 + jj], acc);
                    acc = __fmaf_rn(a1[ee], row[16 + jj], acc);
                    acc = __fmaf_rn(a0[ee], row[jj],      acc);
                    l16[jj] = acc;
                }
            }
            float e_np;
            {
#pragma clang fp contract(off)
#pragma unroll
                for (int jj = 0; jj < 8; ++jj) l16[jj] = l16[jj] + l16[jj + 8];
#pragma unroll
                for (int jj = 0; jj < 4; ++jj) l16[jj] = l16[jj] + l16[jj + 4];
                l16[0] = l16[0] + l16[2];
                l16[1] = l16[1] + l16[3];
                e_np = l16[0] + l16[1];
            }
            float dd;
            {
#pragma clang fp contract(off)
                float t1 = szs + bnk;
                float mm = 2.0f * e_np;
                dd = t1 - mm;
            }
            unsigned long long p =
                ((unsigned long long)__float_as_uint(dd) << 10) | (unsigned int)k;
            pk = (p < pk) ? p : pk;
        }

        // block-wide u64 min: wave butterfly then 4-slot LDS merge
#pragma unroll
        for (int off = 32; off > 0; off >>= 1) {
            unsigned long long o = shfl_down_u64(pk, off);
            pk = (o < pk) ? o : pk;
        }
        if (lane == 0) s_pk[w] = pk;
        __syncthreads();
        if (tid == 0) {
            unsigned long long m = s_pk[0];
            m = (s_pk[1] < m) ? s_pk[1] : m;
            m = (s_pk[2] < m) ? s_pk[2] : m;
            m = (s_pk[3] < m) ? s_pk[3] : m;
            s_min = m;
        }
        __syncthreads();

        // finish (ops identical to verified finish), wave 0 only
        if (w == 0) {
            const int best = (int)(s_min & 1023ull);
            const float zl = zsh[lane];
            const float zq = cb[(size_t)best * DIM + lane];
            float d, o;
            {
#pragma clang fp contract(off)
                d = zq - zl;
                o = zl + d;
            }
            out[(size_t)t * DIM + lane] = o;
            float l2 = d * d;
#pragma unroll
            for (int off = 32; off > 0; off >>= 1)
                l2 += __shfl_down(l2, off);
            if (lane == 0) {
                out[OUT_IDX_OFF + t] = (float)best;
                atomicAdd(loss_sum, (double)l2);
            }
        }
    }

    // ---- last finishing block writes the final loss ----
    __threadfence();
    __syncthreads();
    if (tid == 0) {
        unsigned int old = atomicAdd(done_all, 1u);
        if (old == (unsigned int)(TOKENS / 64) - 1u) {
            double L = atomicAdd(loss_sum, 0.0);   // coherent read-through
            out[OUT_LOSS_OFF] = (float)(2.0 * L / (double)((size_t)TOKENS * DIM));
        }
    }
}

extern "C" void kernel_launch(void* const* d_in, const int* in_sizes, int n_in,
                              void* d_out, int out_size, void* d_ws, size_t ws_size,
                              hipStream_t stream) {
    const float* z  = (const float*)d_in[0];   // [8,8192,64] f32
    const float* cb = (const float*)d_in[1];   // [1024,64] f32
    float* out = (float*)d_out;

    char* ws = (char*)d_ws;
    double* loss_sum = (double*)(ws + WS_LOSS);
    unsigned int* done_all = (unsigned int*)(ws + WS_DONEA);
    float* bnorm = (float*)(ws + WS_BNORM);
    float* bns = (float*)(ws + WS_BNS);
    unsigned short* chi = (unsigned short*)(ws + WS_CHI);
    unsigned short* clo = (unsigned short*)(ws + WS_CLO);

    vq_prep<<<dim3(256), dim3(256), 0, stream>>>(
        cb, chi, clo, bnorm, bns, (unsigned int*)ws);
    vq_fast<<<dim3(TOKENS / 64), dim3(256), 0, stream>>>(
        z, cb, chi, clo, bns, bnorm, out, loss_sum, done_all);
}

// Round 11
// 252.245 us; speedup vs baseline: 1.2204x; 1.2204x over previous
//
#include <hip/hip_runtime.h>

#define TOKENS 65536
#define DIM 64
#define NCODE 1024
// fp16-screen margin (unscaled). Screen error bound: ~192 f32 roundings x
// ulp(3e5 scaled)/2^21 ~ 2.9e-6 worst-case; 1e-5 gives 3.4x headroom.
#define MARGIN 1e-5f
#define MARGINS (MARGIN * 2097152.0f)   // scaled-domain threshold (x 2^21)

#define OUT_IDX_OFF ((size_t)TOKENS * DIM)          // 4194304
#define OUT_LOSS_OFF (OUT_IDX_OFF + TOKENS)         // 4259840

// ws layout (bytes):
#define WS_LOSS   0        // double
#define WS_FLAGC  8        // uint (unused, still zeroed)
#define WS_DONEA  12       // uint (global finisher counter)
#define WS_DGRP   16       // uint[512] (unused; still zeroed) -> 2064
#define WS_BNORM  2064     // f32[1024] -> 6160 (unscaled, exact path)
#define WS_BNS    6160     // f32[1024] -> 10256 (x2^21, screen)
#define WS_CHI    10256    // ushort[65536] -> 141328 (fp16 hi of -8192*c)
#define WS_CLO    141328   // ushort[65536] -> 272400 (fp16 lo)

typedef __attribute__((ext_vector_type(8))) short short8;
typedef __attribute__((ext_vector_type(8))) _Float16 half8;
typedef __attribute__((ext_vector_type(4))) float f32x4;

static __device__ __forceinline__ half8 as_h8(short8 v) {
    return __builtin_bit_cast(half8, v);
}

// ---------------------------------------------------------------------------
// numpy-bitwise f32 sum-of-squares — VERIFIED absmax=0 (round 2). Do not touch.
// ---------------------------------------------------------------------------
__device__ __forceinline__ float np_sumsq64(const float* __restrict__ x) {
#pragma clang fp contract(off)
    float r[8];
#pragma unroll
    for (int j = 0; j < 8; ++j) r[j] = x[j] * x[j];
#pragma unroll
    for (int i = 8; i < 64; i += 8) {
#pragma unroll
        for (int j = 0; j < 8; ++j) {
            float sq = x[i + j] * x[i + j];
            r[j] = r[j] + sq;
        }
    }
    return ((r[0] + r[1]) + (r[2] + r[3])) + ((r[4] + r[5]) + (r[6] + r[7]));
}

// ---------------------------------------------------------------------------
// Prep v2 (UNCHANGED, verified): codebook -> fp16 hi/lo A-frags of (-2*4096*C)
// + bnorm (unscaled, exact path) + bns (= bnorm * 2^21, screen).
// ---------------------------------------------------------------------------
__global__ __launch_bounds__(256) void vq_prep(
    const float* __restrict__ cb, unsigned short* __restrict__ chi,
    unsigned short* __restrict__ clo, float* __restrict__ bnorm,
    float* __restrict__ bns,
    unsigned int* __restrict__ ctrl /* 516 u32 at ws+0 */) {
    int tid = blockIdx.x * 256 + threadIdx.x;   // 0..65535
    if (tid < 516) ctrl[tid] = 0u;
    int j = tid & 7;
    int L = (tid >> 3) & 63;
    int cs = tid >> 9;          // 0..127
    int s = cs & 1, c = cs >> 1;
    int code = c * 16 + (L & 15);
    int d = s * 32 + (L >> 4) * 8 + j;
    float v = -8192.0f * cb[(size_t)code * DIM + d];   // -2c * 4096 (exact)
    _Float16 h = (_Float16)v;                          // RN f32->f16
    float hf = (float)h;
    float lo;
    {
#pragma clang fp contract(off)
        lo = v - hf;                                   // exact in f32
    }
    _Float16 l = (_Float16)lo;
    chi[tid] = __builtin_bit_cast(unsigned short, h);
    clo[tid] = __builtin_bit_cast(unsigned short, l);

    if (tid < NCODE) {
        float bn = np_sumsq64(cb + (size_t)tid * DIM);
        bnorm[tid] = bn;
        bns[tid] = bn * 2097152.0f;                    // x 2^21 (exact)
    }
}

__device__ __forceinline__ void top2_merge(float& a1, float& a2, int& ai,
                                           float b1, float b2, int bi) {
    float n1 = fminf(a1, b1);
    float n2 = fminf(fmaxf(a1, b1), fminf(a2, b2));
    ai = (b1 < a1) ? bi : ai;   // ties keep a (exact ties get flagged anyway)
    a1 = n1; a2 = n2;
}

__device__ __forceinline__ unsigned long long shfl_down_u64(unsigned long long v, int off) {
    unsigned int lo = (unsigned int)v, hi = (unsigned int)(v >> 32);
    lo = __shfl_down(lo, off);
    hi = __shfl_down(hi, off);
    return ((unsigned long long)hi << 32) | lo;
}

// ---------------------------------------------------------------------------
// Fused screen + inline exact, v14 (r10b). r10's fusion passed correctness
// but regressed 5x from SCRATCH SPILL: the tail's float row[64] (x4 by
// e-loop unroll) blew the VGPR budget -> +64MB/dispatch spill traffic
// (WRITE 16.7->65MB, VGPR 52->64, MfmaUtil ~0). Fix: no row array — load
// the codebook row as 4x float4 per g2 slice inside the loop (L2-resident,
// only ~110/1024 blocks run this), and pin the e-loop with unroll 1.
// Per-(token,code) FMA chain/operands verbatim from r9-verified v6 ->
// identical bits. Screen = r3/v9 verbatim. Everything else = r10.
// ---------------------------------------------------------------------------
__global__ __launch_bounds__(256, 4) void vq_fast(
    const float* __restrict__ z, const float* __restrict__ cb,
    const unsigned short* __restrict__ cfrag_hi,
    const unsigned short* __restrict__ cfrag_lo,
    const float* __restrict__ bnorm_s, const float* __restrict__ bnorm,
    float* __restrict__ out, double* __restrict__ loss_sum,
    unsigned int* __restrict__ done_all) {
    __shared__ short8 sh_hi[2][512];   // [buf][(cc*2+step)*64 + lane], 8KB each
    __shared__ short8 sh_lo[2][512];
    __shared__ float bn_lds[NCODE];
    __shared__ int s_best[64];
    __shared__ int s_flag[64];
    __shared__ int s_flist[64];
    __shared__ unsigned int s_fcnt;
    __shared__ float zsh[68];
    __shared__ float s_zs;
    __shared__ unsigned long long s_pk[4];
    __shared__ unsigned long long s_min;

    const int tid = threadIdx.x;
    const int lane = tid & 63;
    const int w = tid >> 6;
    const int t0 = blockIdx.x * 64;
    const int tw = t0 + w * 16;              // this wave's 16 tokens
    const int col = lane & 15;
    const int quad = lane >> 4;

    if (tid == 0) s_fcnt = 0u;

    // stage scaled bnorm into LDS (4 KB)
    ((float4*)bn_lds)[tid] = ((const float4*)bnorm_s)[tid];

    // token B-fragments (fp16 hi/lo of z*512), 2 K-steps, in registers
    half8 zhi[2], zlo[2];
#pragma unroll
    for (int s = 0; s < 2; ++s) {
        const float* zp = z + (size_t)(tw + col) * DIM + s * 32 + quad * 8;
        float4 f0 = ((const float4*)zp)[0];
        float4 f1 = ((const float4*)zp)[1];
        float f[8] = {f0.x, f0.y, f0.z, f0.w, f1.x, f1.y, f1.z, f1.w};
        half8 hh8, ll8;
#pragma unroll
        for (int j = 0; j < 8; ++j) {
            float sv = f[j] * 512.0f;        // exact pow2 scale
            _Float16 hh = (_Float16)sv;      // RN
            float hf = (float)hh;
            float lo;
            {
#pragma clang fp contract(off)
                lo = sv - hf;                // exact in f32
            }
            hh8[j] = hh;
            ll8[j] = (_Float16)lo;
        }
        zhi[s] = hh8; zlo[s] = ll8;
    }

    const short8* CH = (const short8*)cfrag_hi;   // 4096 short8 (64 chunks)
    const short8* CL = (const short8*)cfrag_lo;

    // stage group 0 (4 chunks = 512 short8 per array; 2 per thread per array)
    {
        short8 a0 = CH[tid], a1 = CH[tid + 256];
        short8 b0 = CL[tid], b1 = CL[tid + 256];
        sh_hi[0][tid] = a0; sh_hi[0][tid + 256] = a1;
        sh_lo[0][tid] = b0; sh_lo[0][tid + 256] = b1;
    }
    __syncthreads();

    float m1 = 3.0e38f, m2 = 3.0e38f;
    int bi = 0;
    const int koff = quad * 4;

    for (int g = 0; g < 16; ++g) {
        const int buf = g & 1;
        short8 a0, a1, b0, b1;
        if (g < 15) {               // issue next group's loads first
            const int base = (g + 1) * 512 + tid;
            a0 = CH[base]; a1 = CH[base + 256];
            b0 = CL[base]; b1 = CL[base + 256];
        }
#pragma unroll
        for (int cc = 0; cc < 4; ++cc) {
            const int c = g * 4 + cc;
            short8 ch0 = sh_hi[buf][(cc * 2 + 0) * 64 + lane];
            short8 ch1 = sh_hi[buf][(cc * 2 + 1) * 64 + lane];
            short8 cl0 = sh_lo[buf][(cc * 2 + 0) * 64 + lane];
            short8 cl1 = sh_lo[buf][(cc * 2 + 1) * 64 + lane];
            const int cbase = c * 16 + koff;
            const f32x4 bn = *(const f32x4*)&bn_lds[cbase];
            f32x4 acc = bn;
            acc = __builtin_amdgcn_mfma_f32_16x16x32_f16(as_h8(ch0), zhi[0], acc, 0, 0, 0);
            acc = __builtin_amdgcn_mfma_f32_16x16x32_f16(as_h8(cl0), zhi[0], acc, 0, 0, 0);
            acc = __builtin_amdgcn_mfma_f32_16x16x32_f16(as_h8(ch0), zlo[0], acc, 0, 0, 0);
            acc = __builtin_amdgcn_mfma_f32_16x16x32_f16(as_h8(ch1), zhi[1], acc, 0, 0, 0);
            acc = __builtin_amdgcn_mfma_f32_16x16x32_f16(as_h8(cl1), zhi[1], acc, 0, 0, 0);
            acc = __builtin_amdgcn_mfma_f32_16x16x32_f16(as_h8(ch1), zlo[1], acc, 0, 0, 0);
#pragma unroll
            for (int i = 0; i < 4; ++i) {
                float u = acc[i];
                float om1 = m1;
                bool lt = u < om1;
                float fm = fminf(m2, u);
                m2 = lt ? om1 : fm;
                m1 = lt ? u : om1;
                bi = lt ? (cbase + i) : bi;
            }
        }
        if (g < 15) {
            sh_hi[buf ^ 1][tid] = a0; sh_hi[buf ^ 1][tid + 256] = a1;
            sh_lo[buf ^ 1][tid] = b0; sh_lo[buf ^ 1][tid + 256] = b1;
            __syncthreads();
        }
    }

    // in-wave quad merge (lanes l, l^16, l^32, l^48 share a token column)
    {
        float a1 = m1, a2 = m2;
        int ai = bi;
        {
            float o1 = __shfl_xor(a1, 16); float o2 = __shfl_xor(a2, 16);
            int oi = __shfl_xor(ai, 16);
            top2_merge(a1, a2, ai, o1, o2, oi);
        }
        {
            float o1 = __shfl_xor(a1, 32); float o2 = __shfl_xor(a2, 32);
            int oi = __shfl_xor(ai, 32);
            top2_merge(a1, a2, ai, o1, o2, oi);
        }
        if (quad == 0) {
            const int slot = w * 16 + col;
            int fl = (a2 - a1) < MARGINS;
            if (fl) {
                unsigned int p = atomicAdd(&s_fcnt, 1u);   // LDS, block-scope
                s_flist[p] = slot;
            }
            s_best[slot] = ai;
            s_flag[slot] = fl;
        }
    }
    __syncthreads();

    // epilogue: 2 threads per token, 32 floats each (r6-verified partial
    // structure); flagged deferred to inline exact below.
    const int et = tid >> 1, h = tid & 1;
    float loss_t = 0.0f;
    if (et < 64 && !s_flag[et]) {
        const int B = s_best[et];
        const float4* cq  = (const float4*)(cb + (size_t)B * DIM + h * 32);
        const float4* zq4 = (const float4*)(z + (size_t)(t0 + et) * DIM + h * 32);
        float4* o4 = (float4*)(out + (size_t)(t0 + et) * DIM + h * 32);
#pragma unroll
        for (int jj = 0; jj < 8; ++jj) {
#pragma clang fp contract(off)
            float4 cc = cq[jj];
            float4 zz = zq4[jj];
            float d0 = cc.x - zz.x, d1 = cc.y - zz.y;
            float d2 = cc.z - zz.z, d3 = cc.w - zz.w;
            float4 o;
            o.x = zz.x + d0; o.y = zz.y + d1;
            o.z = zz.z + d2; o.w = zz.w + d3;
            o4[jj] = o;
            loss_t = __fmaf_rn(d0, d0, loss_t);
            loss_t = __fmaf_rn(d1, d1, loss_t);
            loss_t = __fmaf_rn(d2, d2, loss_t);
            loss_t = __fmaf_rn(d3, d3, loss_t);
        }
        if (h == 0) out[OUT_IDX_OFF + t0 + et] = (float)B;
    }
#pragma unroll
    for (int off = 32; off > 0; off >>= 1)
        loss_t += __shfl_down(loss_t, off);
    if (lane == 0 && w < 2) atomicAdd(loss_sum, (double)loss_t);

    // ---- inline exact pass for this block's flagged tokens (usually 0/1).
    // FMA chain/operands VERBATIM from r9-verified v6; codebook row loaded
    // as 4x float4 per g2 slice (no row[64] array -> no spill); e-loop
    // unroll 1 pins live range to one code.
    const unsigned int nf = s_fcnt;
    for (unsigned int fi = 0; fi < nf; ++fi) {
        __syncthreads();                       // zsh reuse across iterations
        const int t = t0 + s_flist[fi];
        if (tid < 4) {
            const float4* zp4 = (const float4*)(z + (size_t)t * DIM + tid * 16);
            float4* dst = (float4*)(zsh + tid * 16);
#pragma unroll
            for (int e = 0; e < 4; ++e) dst[e] = zp4[e];
        }
        __syncthreads();
        if (tid == 0) s_zs = np_sumsq64(zsh);
        __syncthreads();

        const float szs = s_zs;
        const float* zp = zsh;
        unsigned long long pk = ~0ull;

#pragma unroll 1
        for (int e = 0; e < 4; ++e) {
            const int k = e * 256 + tid;          // code index
            const float4* c4 = (const float4*)(cb + (size_t)k * DIM);
            const float bnk = bnorm[k];

            float l16[16];
#pragma unroll
            for (int g2 = 0; g2 < 4; ++g2) {
                float4 v0 = ((const float4*)(zp + 4 * g2))[0];
                float4 v1 = ((const float4*)(zp + 16 + 4 * g2))[0];
                float4 v2 = ((const float4*)(zp + 32 + 4 * g2))[0];
                float4 v3 = ((const float4*)(zp + 48 + 4 * g2))[0];
                float4 r0 = c4[g2];          // row[jj],    jj = 4*g2+ee
                float4 r1 = c4[4 + g2];      // row[16+jj]
                float4 r2 = c4[8 + g2];      // row[32+jj]
                float4 r3 = c4[12 + g2];     // row[48+jj]
                float a0[4] = {v0.x, v0.y, v0.z, v0.w};
                float a1[4] = {v1.x, v1.y, v1.z, v1.w};
                float a2[4] = {v2.x, v2.y, v2.z, v2.w};
                float a3[4] = {v3.x, v3.y, v3.z, v3.w};
                float b0[4] = {r0.x, r0.y, r0.z, r0.w};
                float b1[4] = {r1.x, r1.y, r1.z, r1.w};
                float b2[4] = {r2.x, r2.y, r2.z, r2.w};
                float b3[4] = {r3.x, r3.y, r3.z, r3.w};
#pragma unroll
                for (int ee = 0; ee < 4; ++ee) {
#pragma clang fp contract(off)
                    int jj = 4 * g2 + ee;
                    float acc = a3[ee] * b3[ee];
                    acc = __fmaf_rn(a2[ee], b2[ee], acc);
                    acc = __fmaf_rn(a1[ee], b1[ee], acc);
                    acc = __fmaf_rn(a0[ee], b0[ee], acc);
                    l16[jj] = acc;
                }
            }
            float e_np;
            {
#pragma clang fp contract(off)
#pragma unroll
                for (int jj = 0; jj < 8; ++jj) l16[jj] = l16[jj] + l16[jj + 8];
#pragma unroll
                for (int jj = 0; jj < 4; ++jj) l16[jj] = l16[jj] + l16[jj + 4];
                l16[0] = l16[0] + l16[2];
                l16[1] = l16[1] + l16[3];
                e_np = l16[0] + l16[1];
            }
            float dd;
            {
#pragma clang fp contract(off)
                float t1 = szs + bnk;
                float mm = 2.0f * e_np;
                dd = t1 - mm;
            }
            unsigned long long p =
                ((unsigned long long)__float_as_uint(dd) << 10) | (unsigned int)k;
            pk = (p < pk) ? p : pk;
        }

        // block-wide u64 min: wave butterfly then 4-slot LDS merge
#pragma unroll
        for (int off = 32; off > 0; off >>= 1) {
            unsigned long long o = shfl_down_u64(pk, off);
            pk = (o < pk) ? o : pk;
        }
        if (lane == 0) s_pk[w] = pk;
        __syncthreads();
        if (tid == 0) {
            unsigned long long m = s_pk[0];
            m = (s_pk[1] < m) ? s_pk[1] : m;
            m = (s_pk[2] < m) ? s_pk[2] : m;
            m = (s_pk[3] < m) ? s_pk[3] : m;
            s_min = m;
        }
        __syncthreads();

        // finish (ops identical to verified finish), wave 0 only
        if (w == 0) {
            const int best = (int)(s_min & 1023ull);
            const float zl = zsh[lane];
            const float zq = cb[(size_t)best * DIM + lane];
            float d, o;
            {
#pragma clang fp contract(off)
                d = zq - zl;
                o = zl + d;
            }
            out[(size_t)t * DIM + lane] = o;
            float l2 = d * d;
#pragma unroll
            for (int off = 32; off > 0; off >>= 1)
                l2 += __shfl_down(l2, off);
            if (lane == 0) {
                out[OUT_IDX_OFF + t] = (float)best;
                atomicAdd(loss_sum, (double)l2);
            }
        }
    }

    // ---- last finishing block writes the final loss ----
    __threadfence();
    __syncthreads();
    if (tid == 0) {
        unsigned int old = atomicAdd(done_all, 1u);
        if (old == (unsigned int)(TOKENS / 64) - 1u) {
            double L = atomicAdd(loss_sum, 0.0);   // coherent read-through
            out[OUT_LOSS_OFF] = (float)(2.0 * L / (double)((size_t)TOKENS * DIM));
        }
    }
}

extern "C" void kernel_launch(void* const* d_in, const int* in_sizes, int n_in,
                              void* d_out, int out_size, void* d_ws, size_t ws_size,
                              hipStream_t stream) {
    const float* z  = (const float*)d_in[0];   // [8,8192,64] f32
    const float* cb = (const float*)d_in[1];   // [1024,64] f32
    float* out = (float*)d_out;

    char* ws = (char*)d_ws;
    double* loss_sum = (double*)(ws + WS_LOSS);
    unsigned int* done_all = (unsigned int*)(ws + WS_DONEA);
    float* bnorm = (float*)(ws + WS_BNORM);
    float* bns = (float*)(ws + WS_BNS);
    unsigned short* chi = (unsigned short*)(ws + WS_CHI);
    unsigned short* clo = (unsigned short*)(ws + WS_CLO);

    vq_prep<<<dim3(256), dim3(256), 0, stream>>>(
        cb, chi, clo, bnorm, bns, (unsigned int*)ws);
    vq_fast<<<dim3(TOKENS / 64), dim3(256), 0, stream>>>(
        z, cb, chi, clo, bns, bnorm, out, loss_sum, done_all);
}

// Round 12
// 137.364 us; speedup vs baseline: 2.2410x; 1.8363x over previous
//
#include <hip/hip_runtime.h>

#define TOKENS 65536
#define DIM 64
#define NCODE 1024
// fp16-screen margin (unscaled). Screen error bound: ~192 f32 roundings x
// ulp(3e5 scaled)/2^21 ~ 2.9e-6 worst-case; 1e-5 gives 3.4x headroom.
#define MARGIN 1e-5f
#define MARGINS (MARGIN * 2097152.0f)   // scaled-domain threshold (x 2^21)
#define FLAG_CAP 8192   // block-per-token, no done_grp constraint

#define OUT_IDX_OFF ((size_t)TOKENS * DIM)          // 4194304
#define OUT_LOSS_OFF (OUT_IDX_OFF + TOKENS)         // 4259840

// ws layout (bytes):
#define WS_LOSS   0        // double
#define WS_FLAGC  8        // uint
#define WS_DONEA  12       // uint (global finisher counter)
#define WS_DGRP   16       // uint[512] (unused; still zeroed) -> 2064
#define WS_BNORM  2064     // f32[1024] -> 6160 (unscaled, exact pass)
#define WS_BNS    6160     // f32[1024] -> 10256 (x2^21, screen)
#define WS_CHI    10256    // ushort[65536] -> 141328 (fp16 hi of -8192*c)
#define WS_CLO    141328   // ushort[65536] -> 272400 (fp16 lo)
#define WS_PACKED 272400   // u64[8192] -> 337936 (unused, kept for layout)
#define WS_FLAGS  337936   // int[8192] -> 370704

typedef __attribute__((ext_vector_type(8))) short short8;
typedef __attribute__((ext_vector_type(8))) _Float16 half8;
typedef __attribute__((ext_vector_type(4))) float f32x4;

static __device__ __forceinline__ half8 as_h8(short8 v) {
    return __builtin_bit_cast(half8, v);
}

// ---------------------------------------------------------------------------
// numpy-bitwise f32 sum-of-squares — VERIFIED absmax=0 (round 2). Do not touch.
// ---------------------------------------------------------------------------
__device__ __forceinline__ float np_sumsq64(const float* __restrict__ x) {
#pragma clang fp contract(off)
    float r[8];
#pragma unroll
    for (int j = 0; j < 8; ++j) r[j] = x[j] * x[j];
#pragma unroll
    for (int i = 8; i < 64; i += 8) {
#pragma unroll
        for (int j = 0; j < 8; ++j) {
            float sq = x[i + j] * x[i + j];
            r[j] = r[j] + sq;
        }
    }
    return ((r[0] + r[1]) + (r[2] + r[3])) + ((r[4] + r[5]) + (r[6] + r[7]));
}

// ---------------------------------------------------------------------------
// Prep v2 (UNCHANGED, verified): codebook -> fp16 hi/lo A-frags of (-2*4096*C)
// + bnorm (unscaled, exact pass) + bns (= bnorm * 2^21, screen).
// ---------------------------------------------------------------------------
__global__ __launch_bounds__(256) void vq_prep(
    const float* __restrict__ cb, unsigned short* __restrict__ chi,
    unsigned short* __restrict__ clo, float* __restrict__ bnorm,
    float* __restrict__ bns,
    unsigned int* __restrict__ ctrl /* 516 u32 at ws+0 */) {
    int tid = blockIdx.x * 256 + threadIdx.x;   // 0..65535
    if (tid < 516) ctrl[tid] = 0u;
    int j = tid & 7;
    int L = (tid >> 3) & 63;
    int cs = tid >> 9;          // 0..127
    int s = cs & 1, c = cs >> 1;
    int code = c * 16 + (L & 15);
    int d = s * 32 + (L >> 4) * 8 + j;
    float v = -8192.0f * cb[(size_t)code * DIM + d];   // -2c * 4096 (exact)
    _Float16 h = (_Float16)v;                          // RN f32->f16
    float hf = (float)h;
    float lo;
    {
#pragma clang fp contract(off)
        lo = v - hf;                                   // exact in f32
    }
    _Float16 l = (_Float16)lo;
    chi[tid] = __builtin_bit_cast(unsigned short, h);
    clo[tid] = __builtin_bit_cast(unsigned short, l);

    if (tid < NCODE) {
        float bn = np_sumsq64(cb + (size_t)tid * DIM);
        bnorm[tid] = bn;
        bns[tid] = bn * 2097152.0f;                    // x 2^21 (exact)
    }
}

__device__ __forceinline__ void top2_merge(float& a1, float& a2, int& ai,
                                           float b1, float b2, int bi) {
    float n1 = fminf(a1, b1);
    float n2 = fminf(fmaxf(a1, b1), fminf(a2, b2));
    ai = (b1 < a1) ? bi : ai;   // ties keep a (exact ties get flagged anyway)
    a1 = n1; a2 = n2;
}

// ---------------------------------------------------------------------------
// Fast screen, v9 (r13/r3 VERBATIM — best verified: 51.5us). r4 (code-split),
// r5 (wide block), r7 (global_load_lds DMA), r10/r11 (inline exact fusion —
// spill-poisoned codegen) all regressed. Do not restructure.
// ---------------------------------------------------------------------------
__global__ __launch_bounds__(256, 4) void vq_fast(
    const float* __restrict__ z, const float* __restrict__ cb,
    const unsigned short* __restrict__ cfrag_hi,
    const unsigned short* __restrict__ cfrag_lo,
    const float* __restrict__ bnorm_s, float* __restrict__ out,
    unsigned int* __restrict__ flag_count, int* __restrict__ flag_list,
    unsigned long long* __restrict__ packed_min,
    double* __restrict__ loss_sum, unsigned int flag_cap) {
    __shared__ short8 sh_hi[2][512];   // [buf][(cc*2+step)*64 + lane], 8KB each
    __shared__ short8 sh_lo[2][512];
    __shared__ float bn_lds[NCODE];
    __shared__ int s_best[64];
    __shared__ int s_flag[64];

    const int tid = threadIdx.x;
    const int lane = tid & 63;
    const int w = tid >> 6;
    const int t0 = blockIdx.x * 64;
    const int tw = t0 + w * 16;              // this wave's 16 tokens
    const int col = lane & 15;
    const int quad = lane >> 4;

    // stage scaled bnorm into LDS (4 KB)
    ((float4*)bn_lds)[tid] = ((const float4*)bnorm_s)[tid];

    // token B-fragments (fp16 hi/lo of z*512), 2 K-steps, in registers
    half8 zhi[2], zlo[2];
#pragma unroll
    for (int s = 0; s < 2; ++s) {
        const float* zp = z + (size_t)(tw + col) * DIM + s * 32 + quad * 8;
        float4 f0 = ((const float4*)zp)[0];
        float4 f1 = ((const float4*)zp)[1];
        float f[8] = {f0.x, f0.y, f0.z, f0.w, f1.x, f1.y, f1.z, f1.w};
        half8 hh8, ll8;
#pragma unroll
        for (int j = 0; j < 8; ++j) {
            float sv = f[j] * 512.0f;        // exact pow2 scale
            _Float16 hh = (_Float16)sv;      // RN
            float hf = (float)hh;
            float lo;
            {
#pragma clang fp contract(off)
                lo = sv - hf;                // exact in f32
            }
            hh8[j] = hh;
            ll8[j] = (_Float16)lo;
        }
        zhi[s] = hh8; zlo[s] = ll8;
    }

    const short8* CH = (const short8*)cfrag_hi;   // 4096 short8 (64 chunks)
    const short8* CL = (const short8*)cfrag_lo;

    // stage group 0 (4 chunks = 512 short8 per array; 2 per thread per array)
    {
        short8 a0 = CH[tid], a1 = CH[tid + 256];
        short8 b0 = CL[tid], b1 = CL[tid + 256];
        sh_hi[0][tid] = a0; sh_hi[0][tid + 256] = a1;
        sh_lo[0][tid] = b0; sh_lo[0][tid + 256] = b1;
    }
    __syncthreads();

    float m1 = 3.0e38f, m2 = 3.0e38f;
    int bi = 0;
    const int koff = quad * 4;

    for (int g = 0; g < 16; ++g) {
        const int buf = g & 1;
        short8 a0, a1, b0, b1;
        if (g < 15) {               // issue next group's loads first
            const int base = (g + 1) * 512 + tid;
            a0 = CH[base]; a1 = CH[base + 256];
            b0 = CL[base]; b1 = CL[base + 256];
        }
#pragma unroll
        for (int cc = 0; cc < 4; ++cc) {
            const int c = g * 4 + cc;
            short8 ch0 = sh_hi[buf][(cc * 2 + 0) * 64 + lane];
            short8 ch1 = sh_hi[buf][(cc * 2 + 1) * 64 + lane];
            short8 cl0 = sh_lo[buf][(cc * 2 + 0) * 64 + lane];
            short8 cl1 = sh_lo[buf][(cc * 2 + 1) * 64 + lane];
            const int cbase = c * 16 + koff;
            const f32x4 bn = *(const f32x4*)&bn_lds[cbase];
            f32x4 acc = bn;
            acc = __builtin_amdgcn_mfma_f32_16x16x32_f16(as_h8(ch0), zhi[0], acc, 0, 0, 0);
            acc = __builtin_amdgcn_mfma_f32_16x16x32_f16(as_h8(cl0), zhi[0], acc, 0, 0, 0);
            acc = __builtin_amdgcn_mfma_f32_16x16x32_f16(as_h8(ch0), zlo[0], acc, 0, 0, 0);
            acc = __builtin_amdgcn_mfma_f32_16x16x32_f16(as_h8(ch1), zhi[1], acc, 0, 0, 0);
            acc = __builtin_amdgcn_mfma_f32_16x16x32_f16(as_h8(cl1), zhi[1], acc, 0, 0, 0);
            acc = __builtin_amdgcn_mfma_f32_16x16x32_f16(as_h8(ch1), zlo[1], acc, 0, 0, 0);
#pragma unroll
            for (int i = 0; i < 4; ++i) {
                float u = acc[i];
                float om1 = m1;
                bool lt = u < om1;
                float fm = fminf(m2, u);
                m2 = lt ? om1 : fm;
                m1 = lt ? u : om1;
                bi = lt ? (cbase + i) : bi;
            }
        }
        if (g < 15) {
            sh_hi[buf ^ 1][tid] = a0; sh_hi[buf ^ 1][tid + 256] = a1;
            sh_lo[buf ^ 1][tid] = b0; sh_lo[buf ^ 1][tid + 256] = b1;
            __syncthreads();
        }
    }

    // in-wave quad merge (lanes l, l^16, l^32, l^48 share a token column)
    {
        float a1 = m1, a2 = m2;
        int ai = bi;
        {
            float o1 = __shfl_xor(a1, 16); float o2 = __shfl_xor(a2, 16);
            int oi = __shfl_xor(ai, 16);
            top2_merge(a1, a2, ai, o1, o2, oi);
        }
        {
            float o1 = __shfl_xor(a1, 32); float o2 = __shfl_xor(a2, 32);
            int oi = __shfl_xor(ai, 32);
            top2_merge(a1, a2, ai, o1, o2, oi);
        }
        if (quad == 0) {
            const int slot = w * 16 + col;
            int fl = (a2 - a1) < MARGINS;
            if (fl) {
                unsigned int pos = atomicAdd(flag_count, 1u);
                if (pos >= flag_cap) fl = 0;
                else {
                    flag_list[pos] = t0 + slot;
                    packed_min[pos] = ~0ull;   // harmless (unused)
                }
            }
            s_best[slot] = ai;
            s_flag[slot] = fl;
        }
    }
    __syncthreads();

    // epilogue: 2 threads per token, 32 floats each (r6-verified partial
    // structure); flagged deferred.
    const int et = tid >> 1, h = tid & 1;
    float loss_t = 0.0f;
    if (et < 64 && !s_flag[et]) {
        const int B = s_best[et];
        const float4* cq  = (const float4*)(cb + (size_t)B * DIM + h * 32);
        const float4* zq4 = (const float4*)(z + (size_t)(t0 + et) * DIM + h * 32);
        float4* o4 = (float4*)(out + (size_t)(t0 + et) * DIM + h * 32);
#pragma unroll
        for (int jj = 0; jj < 8; ++jj) {
#pragma clang fp contract(off)
            float4 cc = cq[jj];
            float4 zz = zq4[jj];
            float d0 = cc.x - zz.x, d1 = cc.y - zz.y;
            float d2 = cc.z - zz.z, d3 = cc.w - zz.w;
            float4 o;
            o.x = zz.x + d0; o.y = zz.y + d1;
            o.z = zz.z + d2; o.w = zz.w + d3;
            o4[jj] = o;
            loss_t = __fmaf_rn(d0, d0, loss_t);
            loss_t = __fmaf_rn(d1, d1, loss_t);
            loss_t = __fmaf_rn(d2, d2, loss_t);
            loss_t = __fmaf_rn(d3, d3, loss_t);
        }
        if (h == 0) out[OUT_IDX_OFF + t0 + et] = (float)B;
    }
#pragma unroll
    for (int off = 32; off > 0; off >>= 1)
        loss_t += __shfl_down(loss_t, off);
    if (lane == 0 && w < 2) atomicAdd(loss_sum, (double)loss_t);
}

__device__ __forceinline__ unsigned long long shfl_down_u64(unsigned long long v, int off) {
    unsigned int lo = (unsigned int)v, hi = (unsigned int)(v >> 32);
    lo = __shfl_down(lo, off);
    hi = __shfl_down(hi, off);
    return ((unsigned long long)hi << 32) | lo;
}

// ---------------------------------------------------------------------------
// Exact numpy-bitwise pass, v6 (r9, VERIFIED 136.7us total): ONE BLOCK PER
// FLAGGED TOKEN. Each thread handles codes {tid, 256+tid, 512+tid, 768+tid};
// per-(token,code) arithmetic copied VERBATIM from verified v4 (same input
// bits -> same dd bits); block u64 min (wave butterfly + 4-slot LDS merge)
// is order-invariant -> identical argmin/tie result. Finish ops identical
// to v4's fused finish. done_all orders the final loss write.
// ---------------------------------------------------------------------------
__global__ __launch_bounds__(256) void vq_exact_min(
    const float* __restrict__ z, const float* __restrict__ cb,
    const float* __restrict__ bnorm,
    const unsigned int* __restrict__ flag_count,
    const int* __restrict__ flag_list,
    unsigned long long* __restrict__ packed_min /* unused */,
    unsigned int* __restrict__ done_grp /* unused */,
    unsigned int* __restrict__ done_all,
    float* __restrict__ out, double* __restrict__ loss_sum,
    unsigned int flag_cap) {
    __shared__ float zsh[68];
    __shared__ float s_zs;
    __shared__ unsigned long long s_pk[4];
    __shared__ unsigned long long s_min;

    const int tid = threadIdx.x;
    const int w = tid >> 6;
    const int lane = tid & 63;
    unsigned int count = *flag_count;
    if (count > flag_cap) count = flag_cap;

    if (count == 0) {   // no flagged tokens: block 0 writes the loss
        if (blockIdx.x == 0 && tid == 0) {
            double L = atomicAdd(loss_sum, 0.0);
            out[OUT_LOSS_OFF] = (float)(2.0 * L / (double)((size_t)TOKENS * DIM));
        }
        return;
    }
    if (blockIdx.x >= count) return;

    const int t = flag_list[blockIdx.x];

    // stage token (float4 copy, content-identical to v4 staging)
    if (tid < 4) {
        const float4* zp = (const float4*)(z + (size_t)t * DIM + tid * 16);
        float4* dst = (float4*)(zsh + tid * 16);
#pragma unroll
        for (int e = 0; e < 4; ++e) dst[e] = zp[e];
    }
    __syncthreads();
    if (tid == 0) s_zs = np_sumsq64(zsh);
    __syncthreads();

    const float szs = s_zs;
    const float* zp = zsh;
    unsigned long long pk = ~0ull;

    for (int e = 0; e < 4; ++e) {
        const int k = e * 256 + tid;              // code index
        float row[DIM];
        {
            const float4* c4 = (const float4*)(cb + (size_t)k * DIM);
#pragma unroll
            for (int j = 0; j < 16; ++j) {
                float4 v = c4[j];
                row[4 * j + 0] = v.x; row[4 * j + 1] = v.y;
                row[4 * j + 2] = v.z; row[4 * j + 3] = v.w;
            }
        }
        const float bnk = bnorm[k];

        float l16[16];
#pragma unroll
        for (int g2 = 0; g2 < 4; ++g2) {
            float4 v0 = ((const float4*)(zp + 4 * g2))[0];
            float4 v1 = ((const float4*)(zp + 16 + 4 * g2))[0];
            float4 v2 = ((const float4*)(zp + 32 + 4 * g2))[0];
            float4 v3 = ((const float4*)(zp + 48 + 4 * g2))[0];
            float a0[4] = {v0.x, v0.y, v0.z, v0.w};
            float a1[4] = {v1.x, v1.y, v1.z, v1.w};
            float a2[4] = {v2.x, v2.y, v2.z, v2.w};
            float a3[4] = {v3.x, v3.y, v3.z, v3.w};
#pragma unroll
            for (int ee = 0; ee < 4; ++ee) {
#pragma clang fp contract(off)
                int jj = 4 * g2 + ee;
                float acc = a3[ee] * row[48 + jj];
                acc = __fmaf_rn(a2[ee], row[32 + jj], acc);
                acc = __fmaf_rn(a1[ee], row[16 + jj], acc);
                acc = __fmaf_rn(a0[ee], row[jj],      acc);
                l16[jj] = acc;
            }
        }
        float e_np;
        {
#pragma clang fp contract(off)
#pragma unroll
            for (int jj = 0; jj < 8; ++jj) l16[jj] = l16[jj] + l16[jj + 8];
#pragma unroll
            for (int jj = 0; jj < 4; ++jj) l16[jj] = l16[jj] + l16[jj + 4];
            l16[0] = l16[0] + l16[2];
            l16[1] = l16[1] + l16[3];
            e_np = l16[0] + l16[1];
        }
        float dd;
        {
#pragma clang fp contract(off)
            float t1 = szs + bnk;
            float mm = 2.0f * e_np;
            dd = t1 - mm;
        }
        unsigned long long p =
            ((unsigned long long)__float_as_uint(dd) << 10) | (unsigned int)k;
        pk = (p < pk) ? p : pk;
    }

    // block-wide u64 min: wave butterfly then 4-slot LDS merge
#pragma unroll
    for (int off = 32; off > 0; off >>= 1) {
        unsigned long long o = shfl_down_u64(pk, off);
        pk = (o < pk) ? o : pk;
    }
    if (lane == 0) s_pk[w] = pk;
    __syncthreads();
    if (tid == 0) {
        unsigned long long m = s_pk[0];
        m = (s_pk[1] < m) ? s_pk[1] : m;
        m = (s_pk[2] < m) ? s_pk[2] : m;
        m = (s_pk[3] < m) ? s_pk[3] : m;
        s_min = m;
    }
    __syncthreads();

    // finish (ops identical to v4's fused finish), wave 0 only
    if (w == 0) {
        const int best = (int)(s_min & 1023ull);
        const float zl = zsh[lane];
        const float zq = cb[(size_t)best * DIM + lane];
        float d, o;
        {
#pragma clang fp contract(off)
            d = zq - zl;
            o = zl + d;
        }
        out[(size_t)t * DIM + lane] = o;
        float l2 = d * d;
#pragma unroll
        for (int off = 32; off > 0; off >>= 1)
            l2 += __shfl_down(l2, off);
        if (lane == 0) {
            out[OUT_IDX_OFF + t] = (float)best;
            atomicAdd(loss_sum, (double)l2);
        }
    }

    __threadfence();
    __syncthreads();
    if (tid == 0) {
        unsigned int old = atomicAdd(done_all, 1u);
        if (old == count - 1) {
            double L = atomicAdd(loss_sum, 0.0);   // coherent read-through
            out[OUT_LOSS_OFF] = (float)(2.0 * L / (double)((size_t)TOKENS * DIM));
        }
    }
}

extern "C" void kernel_launch(void* const* d_in, const int* in_sizes, int n_in,
                              void* d_out, int out_size, void* d_ws, size_t ws_size,
                              hipStream_t stream) {
    const float* z  = (const float*)d_in[0];   // [8,8192,64] f32
    const float* cb = (const float*)d_in[1];   // [1024,64] f32
    float* out = (float*)d_out;

    char* ws = (char*)d_ws;
    double* loss_sum = (double*)(ws + WS_LOSS);
    unsigned int* flag_count = (unsigned int*)(ws + WS_FLAGC);
    unsigned int* done_all = (unsigned int*)(ws + WS_DONEA);
    unsigned int* done_grp = (unsigned int*)(ws + WS_DGRP);
    float* bnorm = (float*)(ws + WS_BNORM);
    float* bns = (float*)(ws + WS_BNS);
    unsigned short* chi = (unsigned short*)(ws + WS_CHI);
    unsigned short* clo = (unsigned short*)(ws + WS_CLO);
    unsigned long long* packed = (unsigned long long*)(ws + WS_PACKED);
    int* flag_list = (int*)(ws + WS_FLAGS);

    unsigned int cap = 0;
    if (ws_size > WS_FLAGS + 4) {
        size_t c = (ws_size - WS_FLAGS) / 4;
        cap = (c > FLAG_CAP) ? FLAG_CAP : (unsigned int)c;
    }

    vq_prep<<<dim3(256), dim3(256), 0, stream>>>(
        cb, chi, clo, bnorm, bns, (unsigned int*)ws);
    vq_fast<<<dim3(TOKENS / 64), dim3(256), 0, stream>>>(
        z, cb, chi, clo, bns, out, flag_count, flag_list, packed, loss_sum, cap);
    vq_exact_min<<<dim3(FLAG_CAP), dim3(256), 0, stream>>>(
        z, cb, bnorm, flag_count, flag_list, packed, done_grp, done_all,
        out, loss_sum, cap);
}